// Round 8
// baseline (378.758 us; speedup 1.0000x reference)
//
#include <hip/hip_runtime.h>
#include <stdint.h>

// Fused windowed-signature (depth 2, WIN=5, D=17) + linear head 306->64,
// GEMM on MFMA (bf16 split-precision, 3 products: AhBh+AhBl+AlBh).
//
// R4: M=16 tile (15 windows) -> LDS 22.3 KB -> 6 blocks/CU (was 3 at M=32).
// Same per-window math/cost as R3; occupancy 2.2 -> ~5.5 waves/SIMD.
//
// x[32][16][25][300] f32, W[64][306] f32, b[64] f32 -> out[32][64][25][300] f32.
// mfma_f32_16x16x32_bf16 layouts [m89-verified]:
//   A: row=lane&15, k=(lane>>4)*8+j ; B: col=lane&15, k=(lane>>4)*8+j
//   D: col=lane&15, row=(lane>>4)*4+reg

typedef __attribute__((ext_vector_type(4))) float f32x4;
typedef __attribute__((ext_vector_type(8))) short bf16x8;
typedef __attribute__((ext_vector_type(4))) int i32x4;

namespace {
constexpr int kN = 32, kC = 16, kJ = 25, kT = 300;
constexpr int kOut = 64, kSig = 306, kK = 320;
constexpr int kTile = 15;            // windows per tile (300 = 20*15), M=16
constexpr int kTPS = 20;             // tiles per (n,j) series
constexpr int kTilesTotal = kN * kJ * kTPS;   // 16000
constexpr int kTPB = 4;              // tiles per block -> grid 4000
constexpr int kThreads = 256;
constexpr int kXS = 21, kXP = 20;    // staged x: [t0-2, t0+18], padded row
}

// Swizzled LDS dword offset for sig element (row=window 0..15, s=0..319).
// 16B-slot XOR swizzle; row*320 % 32 == 0 so bank-quad = (slot^row)&7;
// rows r and r+8 alias -> 2 lanes/bank = free (m136).
__device__ __forceinline__ int lds_off(int row, int s) {
  int slot = s >> 2;
  int sl = (slot & ~7) | ((slot ^ row) & 7);
  return row * 320 + sl * 4 + (s & 3);
}

// Truncate-split pack: hi = v & 0xFFFF0000 (bf16 trunc), lo = v - hi (exact),
// packed = hi_bits | (lo_bits >> 16).
__device__ __forceinline__ uint32_t pack_hl(float v) {
  uint32_t vb = __float_as_uint(v);
  uint32_t hi = vb & 0xFFFF0000u;
  float lo = v - __uint_as_float(hi);
  return __builtin_amdgcn_perm(vb, __float_as_uint(lo), 0x07060302u);
}

// W[64][306] f32 -> WB[(k>>3)*64 + col]*8 + (k&7), packed hi|lo, K padded w/ 0.
__global__ __launch_bounds__(256)
void wt_pack_kernel(const float* __restrict__ W, uint32_t* __restrict__ WB) {
  int i = blockIdx.x * 256 + threadIdx.x;
  if (i < kOut * kK) {
    int col = i / kK;
    int k = i - col * kK;
    float v = (k < kSig) ? W[col * kSig + k] : 0.0f;
    WB[((k >> 3) * kOut + col) * 8 + (k & 7)] = pack_hl(v);
  }
}

union FragU { int i[4]; bf16x8 v; };

__device__ __forceinline__ bf16x8 hi_frag(i32x4 v0, i32x4 v1) {
  FragU f;
  f.i[0] = __builtin_amdgcn_perm((uint32_t)v0.y, (uint32_t)v0.x, 0x07060302u);
  f.i[1] = __builtin_amdgcn_perm((uint32_t)v0.w, (uint32_t)v0.z, 0x07060302u);
  f.i[2] = __builtin_amdgcn_perm((uint32_t)v1.y, (uint32_t)v1.x, 0x07060302u);
  f.i[3] = __builtin_amdgcn_perm((uint32_t)v1.w, (uint32_t)v1.z, 0x07060302u);
  return f.v;
}
__device__ __forceinline__ bf16x8 lo_frag(i32x4 v0, i32x4 v1) {
  FragU f;
  f.i[0] = __builtin_amdgcn_perm((uint32_t)v0.y, (uint32_t)v0.x, 0x05040100u);
  f.i[1] = __builtin_amdgcn_perm((uint32_t)v0.w, (uint32_t)v0.z, 0x05040100u);
  f.i[2] = __builtin_amdgcn_perm((uint32_t)v1.y, (uint32_t)v1.x, 0x05040100u);
  f.i[3] = __builtin_amdgcn_perm((uint32_t)v1.w, (uint32_t)v1.z, 0x05040100u);
  return f.v;
}

__global__ __launch_bounds__(kThreads, 6)
void sig_mfma_kernel(const float* __restrict__ x, const uint32_t* __restrict__ WB,
                     const float* __restrict__ bias, float* __restrict__ out) {
  __shared__ uint32_t sig32[16 * 320];   // 20480 B, packed hi|lo, swizzled
  __shared__ float xs[kXS][kXP];         //  1680 B

  const int tid = threadIdx.x;
  const int lane = tid & 63;
  const int wid = tid >> 6;        // wave id = N-tile (16 output cols)
  const int l15 = lane & 15;
  const int l4 = lane >> 4;

  // ---- B-stationary preload: this wave's 16 cols, all K, hi+lo (80 VGPR) ----
  const int col = wid * 16 + l15;
  bf16x8 Bh[10], Bl[10];
#pragma unroll
  for (int st = 0; st < 10; ++st) {
    int kt = st * 4 + l4;
    const i32x4* p = reinterpret_cast<const i32x4*>(WB + ((size_t)(kt * kOut + col)) * 8);
    i32x4 v0 = p[0], v1 = p[1];
    Bh[st] = hi_frag(v0, v1);
    Bl[st] = lo_frag(v0, v1);
  }
  const float myb = bias[col];

  // ---- One-time zero: K-pad s in [306,320) for all 16 rows (row 15's main
  // region may stay garbage: its accumulator rows are masked on store). ----
  if (tid < 16 * 14) {
    int row = tid / 14, s = 306 + (tid - row * 14);
    sig32[lds_off(row, s)] = 0;
  }

  for (int it = 0; it < kTPB; ++it) {
    const int g = blockIdx.x * kTPB + it;
    const int series = g / kTPS;
    const int t0 = (g - series * kTPS) * kTile;
    const int n = series / kJ;
    const int j = series - n * kJ;

    __syncthreads();  // prev tile's LDS readers done before restage

    // ---- Phase 1: stage x window slab (edge-clamped), t in [t0-2, t0+18] ----
    const float* xbase = x + ((size_t)(n * kC) * kJ + j) * kT;
    for (int i = tid; i < kXS * kC; i += kThreads) {
      int c = i / kXS, tt = i - c * kXS;
      int tg = t0 - 2 + tt;
      tg = tg < 0 ? 0 : (tg > kT - 1 ? kT - 1 : tg);
      xs[tt][c] = xbase[c * kJ * kT + tg];
    }
    __syncthreads();

    // ---- Phase 2: build packed sig rows. 16 threads/window, single pass. ----
    {
      const int w = tid >> 4;        // window 0..15 (only <15 active)
      if (w < kTile) {
        const int sub = tid & 15;
        const int hb = sub & 1;        // channel half (8 channels)
        const int r = sub >> 1;        // a-row group

        // Level 1 (s = 0..16): endpoint (1, p5). One write per thread.
        sig32[lds_off(w, sub)] = pack_hl(sub == 0 ? 1.0f : xs[w + 4][sub - 1]);
        if (sub == 0) sig32[lds_off(w, 16)] = pack_hl(xs[w + 4][15]);

        // d[k][c] for this half: d1 = q1 (basepoint 0), dk = qk - q(k-1).
        float d[5][8];
        {
          float4 a0 = *reinterpret_cast<const float4*>(&xs[w][hb * 8]);
          float4 a1 = *reinterpret_cast<const float4*>(&xs[w][hb * 8 + 4]);
          float pv[8] = {a0.x, a0.y, a0.z, a0.w, a1.x, a1.y, a1.z, a1.w};
#pragma unroll
          for (int c = 0; c < 8; ++c) d[0][c] = pv[c];
#pragma unroll
          for (int k = 1; k < 5; ++k) {
            float4 b0 = *reinterpret_cast<const float4*>(&xs[w + k][hb * 8]);
            float4 b1 = *reinterpret_cast<const float4*>(&xs[w + k][hb * 8 + 4]);
            float cv[8] = {b0.x, b0.y, b0.z, b0.w, b1.x, b1.y, b1.z, b1.w};
#pragma unroll
            for (int c = 0; c < 8; ++c) { d[k][c] = cv[c] - pv[c]; pv[c] = cv[c]; }
          }
        }

        const int nrows = (r == 0) ? 3 : 2;
        for (int ii = 0; ii < nrows; ++ii) {
          const int a = r + 8 * ii;    // r==0,ii==2 -> a=16
          float u[5];
          if (a == 0) {
            u[0] = 0.0f; u[1] = 0.125f; u[2] = 0.375f; u[3] = 0.625f; u[4] = 0.875f;
          } else {
            const int ca = a - 1;
            float p0 = xs[w][ca], p1 = xs[w + 1][ca], p2 = xs[w + 2][ca];
            float p3 = xs[w + 3][ca], p4 = xs[w + 4][ca];
            u[0] = 0.5f * p0;
            u[1] = 0.5f * (p0 + p1);
            u[2] = 0.5f * (p1 + p2);
            u[3] = 0.5f * (p2 + p3);
            u[4] = 0.5f * (p3 + p4);
          }
          const int sbase = 17 + a * 17;
          if (hb == 0) {  // b==0 column: d_k[0] = {0,.25,.25,.25,.25}
            sig32[lds_off(w, sbase)] = pack_hl(0.25f * (u[1] + u[2] + u[3] + u[4]));
          }
#pragma unroll
          for (int bj = 0; bj < 8; ++bj) {
            float val = u[0] * d[0][bj];
            val = fmaf(u[1], d[1][bj], val);
            val = fmaf(u[2], d[2][bj], val);
            val = fmaf(u[3], d[3][bj], val);
            val = fmaf(u[4], d[4][bj], val);
            sig32[lds_off(w, sbase + 1 + hb * 8 + bj)] = pack_hl(val);
          }
        }
      }
    }
    __syncthreads();

    // ---- Phase 3: MFMA. One 16x16 M-tile x this wave's 16 cols. ----
    f32x4 acc = {0.f, 0.f, 0.f, 0.f};
#pragma unroll
    for (int st = 0; st < 10; ++st) {
      const int slotb = st * 8 + (l4 << 1);
      const int row = l15;
      const int sl0 = (slotb & ~7) | ((slotb ^ row) & 7);
      const int sl1 = ((slotb + 1) & ~7) | (((slotb + 1) ^ row) & 7);
      i32x4 v0 = *reinterpret_cast<const i32x4*>(&sig32[row * 320 + sl0 * 4]);
      i32x4 v1 = *reinterpret_cast<const i32x4*>(&sig32[row * 320 + sl1 * 4]);
      bf16x8 Ah = hi_frag(v0, v1), Al = lo_frag(v0, v1);
      acc = __builtin_amdgcn_mfma_f32_16x16x32_bf16(Ah, Bh[st], acc, 0, 0, 0);
      acc = __builtin_amdgcn_mfma_f32_16x16x32_bf16(Ah, Bl[st], acc, 0, 0, 0);
      acc = __builtin_amdgcn_mfma_f32_16x16x32_bf16(Al, Bh[st], acc, 0, 0, 0);
    }

    // ---- Store: lane holds rows (l4*4 + reg), col = o, t = t0 + row.
    // t0 odd for odd tiles -> scalar dword stores (L2 merges to full lines).
    // Row 15 (l4==3, reg==3) is the unused 16th window -> masked. ----
    const size_t obase = ((size_t)(n * kOut + col) * kJ + j) * kT;
    float* dst = out + obase + t0 + (l4 << 2);
    dst[0] = acc.x + myb;
    dst[1] = acc.y + myb;
    dst[2] = acc.z + myb;
    if (l4 != 3) dst[3] = acc.w + myb;
  }
}

extern "C" void kernel_launch(void* const* d_in, const int* in_sizes, int n_in,
                              void* d_out, int out_size, void* d_ws, size_t ws_size,
                              hipStream_t stream) {
  const float* x = (const float*)d_in[0];
  const float* W = (const float*)d_in[1];
  const float* bias = (const float*)d_in[2];
  float* out = (float*)d_out;
  uint32_t* WB = (uint32_t*)d_ws;   // 320*64*4 = 81920 B

  {
    dim3 grid((kOut * kK + 255) / 256);   // 80 blocks
    hipLaunchKernelGGL(wt_pack_kernel, grid, dim3(256), 0, stream, W, WB);
  }
  {
    dim3 grid(kTilesTotal / kTPB);        // 4000 blocks
    hipLaunchKernelGGL(sig_mfma_kernel, grid, dim3(kThreads), 0, stream,
                       x, WB, bias, out);
  }
}

// Round 9
// 250.750 us; speedup vs baseline: 1.5105x; 1.5105x over previous
//
#include <hip/hip_runtime.h>
#include <stdint.h>

// Fused windowed-signature (depth 2, WIN=5, D=17) + linear head 306->64,
// GEMM on MFMA (bf16 split-precision, 3 products: AhBh+AhBl+AlBh).
//
// R5 = R4 (M=16 tile, LDS 22.5 KB) with __launch_bounds__(256,4).
// R4's (256,6) capped VGPR at 40 -> Bh/Bl spilled to scratch -> 1.1 GB HBM
// traffic/launch. Bound 4 caps at 128; kernel needs ~85 -> no spill, and
// LDS permits up to 7 blocks/CU (HW will pick 4-6).
//
// x[32][16][25][300] f32, W[64][306] f32, b[64] f32 -> out[32][64][25][300] f32.
// mfma_f32_16x16x32_bf16 layouts [m89-verified]:
//   A: row=lane&15, k=(lane>>4)*8+j ; B: col=lane&15, k=(lane>>4)*8+j
//   D: col=lane&15, row=(lane>>4)*4+reg

typedef __attribute__((ext_vector_type(4))) float f32x4;
typedef __attribute__((ext_vector_type(8))) short bf16x8;
typedef __attribute__((ext_vector_type(4))) int i32x4;

namespace {
constexpr int kN = 32, kC = 16, kJ = 25, kT = 300;
constexpr int kOut = 64, kSig = 306, kK = 320;
constexpr int kTile = 15;            // windows per tile (300 = 20*15), M=16
constexpr int kTPS = 20;             // tiles per (n,j) series
constexpr int kTilesTotal = kN * kJ * kTPS;   // 16000
constexpr int kTPB = 4;              // tiles per block -> grid 4000
constexpr int kThreads = 256;
constexpr int kXS = 21, kXP = 20;    // staged x: [t0-2, t0+18], padded row
}

// Swizzled LDS dword offset for sig element (row=window 0..15, s=0..319).
// 16B-slot XOR swizzle; row*320 % 32 == 0 so bank-quad = (slot^row)&7;
// rows r and r+8 alias -> 2 lanes/bank = free (m136).
__device__ __forceinline__ int lds_off(int row, int s) {
  int slot = s >> 2;
  int sl = (slot & ~7) | ((slot ^ row) & 7);
  return row * 320 + sl * 4 + (s & 3);
}

// Truncate-split pack: hi = v & 0xFFFF0000 (bf16 trunc), lo = v - hi (exact),
// packed = hi_bits | (lo_bits >> 16).
__device__ __forceinline__ uint32_t pack_hl(float v) {
  uint32_t vb = __float_as_uint(v);
  uint32_t hi = vb & 0xFFFF0000u;
  float lo = v - __uint_as_float(hi);
  return __builtin_amdgcn_perm(vb, __float_as_uint(lo), 0x07060302u);
}

// W[64][306] f32 -> WB[(k>>3)*64 + col]*8 + (k&7), packed hi|lo, K padded w/ 0.
__global__ __launch_bounds__(256)
void wt_pack_kernel(const float* __restrict__ W, uint32_t* __restrict__ WB) {
  int i = blockIdx.x * 256 + threadIdx.x;
  if (i < kOut * kK) {
    int col = i / kK;
    int k = i - col * kK;
    float v = (k < kSig) ? W[col * kSig + k] : 0.0f;
    WB[((k >> 3) * kOut + col) * 8 + (k & 7)] = pack_hl(v);
  }
}

union FragU { int i[4]; bf16x8 v; };

__device__ __forceinline__ bf16x8 hi_frag(i32x4 v0, i32x4 v1) {
  FragU f;
  f.i[0] = __builtin_amdgcn_perm((uint32_t)v0.y, (uint32_t)v0.x, 0x07060302u);
  f.i[1] = __builtin_amdgcn_perm((uint32_t)v0.w, (uint32_t)v0.z, 0x07060302u);
  f.i[2] = __builtin_amdgcn_perm((uint32_t)v1.y, (uint32_t)v1.x, 0x07060302u);
  f.i[3] = __builtin_amdgcn_perm((uint32_t)v1.w, (uint32_t)v1.z, 0x07060302u);
  return f.v;
}
__device__ __forceinline__ bf16x8 lo_frag(i32x4 v0, i32x4 v1) {
  FragU f;
  f.i[0] = __builtin_amdgcn_perm((uint32_t)v0.y, (uint32_t)v0.x, 0x05040100u);
  f.i[1] = __builtin_amdgcn_perm((uint32_t)v0.w, (uint32_t)v0.z, 0x05040100u);
  f.i[2] = __builtin_amdgcn_perm((uint32_t)v1.y, (uint32_t)v1.x, 0x05040100u);
  f.i[3] = __builtin_amdgcn_perm((uint32_t)v1.w, (uint32_t)v1.z, 0x05040100u);
  return f.v;
}

__global__ __launch_bounds__(kThreads, 4)
void sig_mfma_kernel(const float* __restrict__ x, const uint32_t* __restrict__ WB,
                     const float* __restrict__ bias, float* __restrict__ out) {
  __shared__ uint32_t sig32[16 * 320];   // 20480 B, packed hi|lo, swizzled
  __shared__ float xs[kXS][kXP];         //  1680 B

  const int tid = threadIdx.x;
  const int lane = tid & 63;
  const int wid = tid >> 6;        // wave id = N-tile (16 output cols)
  const int l15 = lane & 15;
  const int l4 = lane >> 4;

  // ---- B-stationary preload: this wave's 16 cols, all K, hi+lo (80 VGPR) ----
  const int col = wid * 16 + l15;
  bf16x8 Bh[10], Bl[10];
#pragma unroll
  for (int st = 0; st < 10; ++st) {
    int kt = st * 4 + l4;
    const i32x4* p = reinterpret_cast<const i32x4*>(WB + ((size_t)(kt * kOut + col)) * 8);
    i32x4 v0 = p[0], v1 = p[1];
    Bh[st] = hi_frag(v0, v1);
    Bl[st] = lo_frag(v0, v1);
  }
  const float myb = bias[col];

  // ---- One-time zero: K-pad s in [306,320) for all 16 rows (row 15's main
  // region may stay garbage: its accumulator rows are masked on store). ----
  if (tid < 16 * 14) {
    int row = tid / 14, s = 306 + (tid - row * 14);
    sig32[lds_off(row, s)] = 0;
  }

  for (int it = 0; it < kTPB; ++it) {
    const int g = blockIdx.x * kTPB + it;
    const int series = g / kTPS;
    const int t0 = (g - series * kTPS) * kTile;
    const int n = series / kJ;
    const int j = series - n * kJ;

    __syncthreads();  // prev tile's LDS readers done before restage

    // ---- Phase 1: stage x window slab (edge-clamped), t in [t0-2, t0+18] ----
    const float* xbase = x + ((size_t)(n * kC) * kJ + j) * kT;
    for (int i = tid; i < kXS * kC; i += kThreads) {
      int c = i / kXS, tt = i - c * kXS;
      int tg = t0 - 2 + tt;
      tg = tg < 0 ? 0 : (tg > kT - 1 ? kT - 1 : tg);
      xs[tt][c] = xbase[c * kJ * kT + tg];
    }
    __syncthreads();

    // ---- Phase 2: build packed sig rows. 16 threads/window, single pass. ----
    {
      const int w = tid >> 4;        // window 0..15 (only <15 active)
      if (w < kTile) {
        const int sub = tid & 15;
        const int hb = sub & 1;        // channel half (8 channels)
        const int r = sub >> 1;        // a-row group

        // Level 1 (s = 0..16): endpoint (1, p5). One write per thread.
        sig32[lds_off(w, sub)] = pack_hl(sub == 0 ? 1.0f : xs[w + 4][sub - 1]);
        if (sub == 0) sig32[lds_off(w, 16)] = pack_hl(xs[w + 4][15]);

        // d[k][c] for this half: d1 = q1 (basepoint 0), dk = qk - q(k-1).
        float d[5][8];
        {
          float4 a0 = *reinterpret_cast<const float4*>(&xs[w][hb * 8]);
          float4 a1 = *reinterpret_cast<const float4*>(&xs[w][hb * 8 + 4]);
          float pv[8] = {a0.x, a0.y, a0.z, a0.w, a1.x, a1.y, a1.z, a1.w};
#pragma unroll
          for (int c = 0; c < 8; ++c) d[0][c] = pv[c];
#pragma unroll
          for (int k = 1; k < 5; ++k) {
            float4 b0 = *reinterpret_cast<const float4*>(&xs[w + k][hb * 8]);
            float4 b1 = *reinterpret_cast<const float4*>(&xs[w + k][hb * 8 + 4]);
            float cv[8] = {b0.x, b0.y, b0.z, b0.w, b1.x, b1.y, b1.z, b1.w};
#pragma unroll
            for (int c = 0; c < 8; ++c) { d[k][c] = cv[c] - pv[c]; pv[c] = cv[c]; }
          }
        }

        const int nrows = (r == 0) ? 3 : 2;
        for (int ii = 0; ii < nrows; ++ii) {
          const int a = r + 8 * ii;    // r==0,ii==2 -> a=16
          float u[5];
          if (a == 0) {
            u[0] = 0.0f; u[1] = 0.125f; u[2] = 0.375f; u[3] = 0.625f; u[4] = 0.875f;
          } else {
            const int ca = a - 1;
            float p0 = xs[w][ca], p1 = xs[w + 1][ca], p2 = xs[w + 2][ca];
            float p3 = xs[w + 3][ca], p4 = xs[w + 4][ca];
            u[0] = 0.5f * p0;
            u[1] = 0.5f * (p0 + p1);
            u[2] = 0.5f * (p1 + p2);
            u[3] = 0.5f * (p2 + p3);
            u[4] = 0.5f * (p3 + p4);
          }
          const int sbase = 17 + a * 17;
          if (hb == 0) {  // b==0 column: d_k[0] = {0,.25,.25,.25,.25}
            sig32[lds_off(w, sbase)] = pack_hl(0.25f * (u[1] + u[2] + u[3] + u[4]));
          }
#pragma unroll
          for (int bj = 0; bj < 8; ++bj) {
            float val = u[0] * d[0][bj];
            val = fmaf(u[1], d[1][bj], val);
            val = fmaf(u[2], d[2][bj], val);
            val = fmaf(u[3], d[3][bj], val);
            val = fmaf(u[4], d[4][bj], val);
            sig32[lds_off(w, sbase + 1 + hb * 8 + bj)] = pack_hl(val);
          }
        }
      }
    }
    __syncthreads();

    // ---- Phase 3: MFMA. One 16x16 M-tile x this wave's 16 cols. ----
    f32x4 acc = {0.f, 0.f, 0.f, 0.f};
#pragma unroll
    for (int st = 0; st < 10; ++st) {
      const int slotb = st * 8 + (l4 << 1);
      const int row = l15;
      const int sl0 = (slotb & ~7) | ((slotb ^ row) & 7);
      const int sl1 = ((slotb + 1) & ~7) | (((slotb + 1) ^ row) & 7);
      i32x4 v0 = *reinterpret_cast<const i32x4*>(&sig32[row * 320 + sl0 * 4]);
      i32x4 v1 = *reinterpret_cast<const i32x4*>(&sig32[row * 320 + sl1 * 4]);
      bf16x8 Ah = hi_frag(v0, v1), Al = lo_frag(v0, v1);
      acc = __builtin_amdgcn_mfma_f32_16x16x32_bf16(Ah, Bh[st], acc, 0, 0, 0);
      acc = __builtin_amdgcn_mfma_f32_16x16x32_bf16(Ah, Bl[st], acc, 0, 0, 0);
      acc = __builtin_amdgcn_mfma_f32_16x16x32_bf16(Al, Bh[st], acc, 0, 0, 0);
    }

    // ---- Store: lane holds rows (l4*4 + reg), col = o, t = t0 + row.
    // t0 odd for odd tiles -> scalar dword stores (L2 merges to full lines).
    // Row 15 (l4==3, reg==3) is the unused 16th window -> masked. ----
    const size_t obase = ((size_t)(n * kOut + col) * kJ + j) * kT;
    float* dst = out + obase + t0 + (l4 << 2);
    dst[0] = acc.x + myb;
    dst[1] = acc.y + myb;
    dst[2] = acc.z + myb;
    if (l4 != 3) dst[3] = acc.w + myb;
  }
}

extern "C" void kernel_launch(void* const* d_in, const int* in_sizes, int n_in,
                              void* d_out, int out_size, void* d_ws, size_t ws_size,
                              hipStream_t stream) {
  const float* x = (const float*)d_in[0];
  const float* W = (const float*)d_in[1];
  const float* bias = (const float*)d_in[2];
  float* out = (float*)d_out;
  uint32_t* WB = (uint32_t*)d_ws;   // 320*64*4 = 81920 B

  {
    dim3 grid((kOut * kK + 255) / 256);   // 80 blocks
    hipLaunchKernelGGL(wt_pack_kernel, grid, dim3(256), 0, stream, W, WB);
  }
  {
    dim3 grid(kTilesTotal / kTPB);        // 4000 blocks
    hipLaunchKernelGGL(sig_mfma_kernel, grid, dim3(kThreads), 0, stream,
                       x, WB, bias, out);
  }
}